// Round 10
// baseline (230.926 us; speedup 1.0000x reference)
//
#include <hip/hip_runtime.h>
#include <math.h>

// Problem constants
#define BATCH 512
#define M 128
#define D 512
#define PITER 9           // power iterations (L inflated 1.15x; converged lam is step-independent)
#define NRUN 58           // FISTA iterations (rate ~0.69 -> 0.69^58 ~ 4e-10; reference runs 400)
#define KC 64             // k-columns per staging chunk
#define NCH (D / KC)      // 8 chunks
#define SSTR 72           // staging row stride in halfs (144 B): 16B-aligned, even bank-quad spread
#define GSH 136           // G fp16 LDS row stride in halfs (272 B): 16B-aligned rows, 2-way banks
#define SCL 0.0009765625f // 2^-10 per-iteration power scaling

typedef __attribute__((ext_vector_type(8))) _Float16 h8;
typedef __attribute__((ext_vector_type(4))) float f4;

// ===== fused; build = 4-wave MFMA (depth-2 prefetch), solve = ONE wave, barrier-free,
// software-pipelined: per-quad FISTA+publish overlaps the next quad's MFMAs =====
__launch_bounds__(256, 2)
__global__ void fused_kernel(const float* __restrict__ pred,
                             const float* __restrict__ ctr,
                             float* __restrict__ out)
{
    // union{ fp16 staging 2x18432 B , fp16 G 128xGSH = 34816 B }
    __shared__ __align__(16) char uni[2 * M * SSTR * 2];   // 36864 B
    __shared__ __align__(16) float p_s[D];
    __shared__ __align__(16) _Float16 yh[M];               // y broadcast vector (fp16)
    __shared__ float mask_s[M];
    __shared__ float b_s[M];
    __shared__ float wredA[4];

    _Float16* hiS = (_Float16*)uni;                        // [2][M*SSTR] during build
    _Float16* g16 = (_Float16*)uni;                        // [M][GSH] after build

    const int tid = threadIdx.x;
    const int blk = blockIdx.x;
    const int w = tid >> 6, l = tid & 63;                  // wave, lane
    const int row = tid >> 1;                              // staging row (0..127)
    const int sg = tid & 1;                                // 32-col half of the 64-col chunk
    const int fm = l & 15;                                 // MFMA fragment row/col
    const int fq = l >> 4;                                 // MFMA k-quad

    const float* predRow = pred + (size_t)blk * D;
    const float* ctrBase = ctr + (size_t)blk * (size_t)(M * D);

    // ---- stage p (2 elems/thread), ||p||^2 -> tid 0 register ----
    float pv0 = predRow[tid];
    float pv1 = predRow[tid + 256];
    p_s[tid] = pv0;
    p_s[tid + 256] = pv1;
    float v = pv0 * pv0 + pv1 * pv1;
    #pragma unroll
    for (int off = 32; off > 0; off >>= 1) v += __shfl_xor(v, off, 64);
    if (l == 0) wredA[w] = v;
    __syncthreads();
    float pn2 = 0.0f;
    if (tid == 0) {
        #pragma unroll
        for (int i = 0; i < 4; ++i) pn2 += wredA[i];
    }

    // ---- build: G = (masked C_fp16)(masked C_fp16)^T via MFMA, depth-2 prefetch ----
    f4 acc[2][8];
    #pragma unroll
    for (int i = 0; i < 2; ++i)
        #pragma unroll
        for (int jx = 0; jx < 8; ++jx)
            acc[i][jx] = (f4)0.0f;

    float rs = 0.0f, bp = 0.0f;
    const float* src = ctrBase + (size_t)row * D + 32 * sg;  // this thread's 32-col strip base
    f4 buf[3][8];                                            // 3-deep rotation (static idx via full unroll)
    #pragma unroll
    for (int j = 0; j < 8; ++j) buf[0][j] = *(const f4*)(src + 4 * j);
    #pragma unroll
    for (int j = 0; j < 8; ++j) buf[1][j] = *(const f4*)(src + 64 + 4 * j);

    #pragma unroll
    for (int kc = 0; kc < NCH; ++kc) {
        const int cb = kc % 3;
        _Float16* hc = hiS + (kc & 1) * (M * SSTR);
        // convert + stage 32 halfs
        #pragma unroll
        for (int j = 0; j < 4; ++j) {
            f4 x = buf[cb][2 * j], y = buf[cb][2 * j + 1];
            h8 hv = {(_Float16)x.x, (_Float16)x.y, (_Float16)x.z, (_Float16)x.w,
                     (_Float16)y.x, (_Float16)y.y, (_Float16)y.z, (_Float16)y.w};
            *(h8*)(hc + row * SSTR + 32 * sg + 8 * j) = hv;
        }
        // row-abs-sum and b-dot
        #pragma unroll
        for (int j = 0; j < 8; ++j) {
            f4 x = buf[cb][j];
            rs += fabsf(x.x) + fabsf(x.y) + fabsf(x.z) + fabsf(x.w);
            f4 pp = *(const f4*)(p_s + 64 * kc + 32 * sg + 4 * j);
            bp += x.x * pp.x + x.y * pp.y + x.z * pp.z + x.w * pp.w;
        }
        // issue chunk kc+2 loads BEFORE the barrier: ~2 chunks of work cover HBM latency
        if (kc + 2 < NCH) {
            const int nb = (kc + 2) % 3;
            #pragma unroll
            for (int j = 0; j < 8; ++j) buf[nb][j] = *(const f4*)(src + 64 * (kc + 2) + 4 * j);
        }
        __syncthreads();   // staged data visible; dbuf -> 1 barrier/chunk
        // MFMA: rows [32w,32w+32) x all 128 cols
        #pragma unroll
        for (int ks = 0; ks < 2; ++ks) {
            h8 Ah[2];
            #pragma unroll
            for (int t = 0; t < 2; ++t)
                Ah[t] = *(const h8*)(hc + (32 * w + 16 * t + fm) * SSTR + 32 * ks + 8 * fq);
            #pragma unroll
            for (int tc = 0; tc < 8; ++tc) {
                h8 Bh = *(const h8*)(hc + (16 * tc + fm) * SSTR + 32 * ks + 8 * fq);
                acc[0][tc] = __builtin_amdgcn_mfma_f32_16x16x32_f16(Ah[0], Bh, acc[0][tc], 0, 0, 0);
                acc[1][tc] = __builtin_amdgcn_mfma_f32_16x16x32_f16(Ah[1], Bh, acc[1][tc], 0, 0, 0);
            }
        }
    }

    // ---- row mask + b (pairwise xor over the 2 col-halves) ----
    rs += __shfl_xor(rs, 1, 64);
    bp += __shfl_xor(bp, 1, 64);
    const bool okr = rs > 1e-7f;
    if (sg == 0) {
        mask_s[row] = okr ? 1.0f : 0.0f;
        b_s[row] = okr ? -bp : 0.0f;      // b = C_masked * (-pred)
    }
    if (tid < M) yh[tid] = (_Float16)1.0f;   // power-iteration v0 = ones
    __syncthreads();   // mask/b/y0 ready; hiS dead -> g16 may overwrite

    // hoist masks (C/D layout: col=lane&15, row=(lane>>4)*4+reg)
    float mc[8], mr[2][4];
    #pragma unroll
    for (int tc = 0; tc < 8; ++tc) mc[tc] = mask_s[16 * tc + fm];
    #pragma unroll
    for (int t = 0; t < 2; ++t)
        #pragma unroll
        for (int r = 0; r < 4; ++r) mr[t][r] = mask_s[32 * w + 16 * t + 4 * fq + r];

    // ---- masked G -> fp16 LDS, full 128x128, single barrier ----
    #pragma unroll
    for (int t = 0; t < 2; ++t)
        #pragma unroll
        for (int r = 0; r < 4; ++r) {
            const int grow = 32 * w + 16 * t + 4 * fq + r;
            const float mrr = mr[t][r];
            #pragma unroll
            for (int tc = 0; tc < 8; ++tc)
                g16[grow * GSH + 16 * tc + fm] = (_Float16)(acc[t][tc][r] * mrr * mc[tc]);
        }
    __syncthreads();

    if (w != 0) return;    // waves 1-3 done; no barriers below (wave-internal only)

    // ---- wave-0 solo solve ----
    // B-frags of G (symmetric): gb[t][kt] = G[16t+fm][32kt+8fq .. +8)  (128 regs)
    h8 gb[8][4];
    #pragma unroll
    for (int t = 0; t < 8; ++t)
        #pragma unroll
        for (int kt = 0; kt < 4; ++kt)
            gb[t][kt] = *(const h8*)(g16 + (16 * t + fm) * GSH + 32 * kt + 8 * fq);

    float b8[8];
    #pragma unroll
    for (int t = 0; t < 8; ++t) b8[t] = b_s[16 * t + fm];

    h8 ya[4];
    // fence + load ya: one LDS drain per iteration; sched_barrier per rule #18
    auto load_ya = [&]() {
        asm volatile("s_waitcnt lgkmcnt(0)" ::: "memory");
        __builtin_amdgcn_sched_barrier(0);
        #pragma unroll
        for (int kt = 0; kt < 4; ++kt) ya[kt] = *(const h8*)(yh + 32 * kt + 8 * fq);
    };
    auto wsum = [&](float x) {
        #pragma unroll
        for (int off = 1; off < 64; off <<= 1) x += __shfl_xor(x, off, 64);
        return x;
    };

    // ---- power iteration (unnormalized, 2^-10 per-step scaling) ----
    // per-quad: 16 MFMAs, then scale+publish that quad while next quad's MFMAs issue
    float v8[8];
    #pragma unroll
    for (int t = 0; t < 8; ++t) v8[t] = 1.0f;
    for (int it = 0; it < PITER; ++it) {
        load_ya();
        #pragma unroll
        for (int tq = 0; tq < 2; ++tq) {
            f4 c[4];
            #pragma unroll
            for (int j = 0; j < 4; ++j) c[j] = (f4)0.0f;
            #pragma unroll
            for (int kt = 0; kt < 4; ++kt)
                #pragma unroll
                for (int j = 0; j < 4; ++j)
                    c[j] = __builtin_amdgcn_mfma_f32_16x16x32_f16(ya[kt], gb[4 * tq + j][kt], c[j], 0, 0, 0);
            #pragma unroll
            for (int j = 0; j < 4; ++j) v8[4 * tq + j] = c[j][0] * SCL;
            if (l < 16) {
                #pragma unroll
                for (int j = 0; j < 4; ++j) yh[16 * (4 * tq + j) + l] = (_Float16)v8[4 * tq + j];
            }
        }
    }
    float u8[8];
    float step;
    {
        load_ya();                         // u = G v (raw)
        f4 c[8];
        #pragma unroll
        for (int t = 0; t < 8; ++t) c[t] = (f4)0.0f;
        #pragma unroll
        for (int kt = 0; kt < 4; ++kt)
            #pragma unroll
            for (int t = 0; t < 8; ++t)
                c[t] = __builtin_amdgcn_mfma_f32_16x16x32_f16(ya[kt], gb[t][kt], c[t], 0, 0, 0);
        #pragma unroll
        for (int t = 0; t < 8; ++t) u8[t] = c[t][0];
        float xv = 0.0f, xu = 0.0f;
        if (l < 16) {                      // rows counted once (fq==0 lanes)
            #pragma unroll
            for (int t = 0; t < 8; ++t) { xv += v8[t] * v8[t]; xu += u8[t] * u8[t]; }
        }
        const float nv = wsum(xv);
        const float nu = wsum(xu);
        const float L = sqrtf(nu / fmaxf(nv, 1e-30f));
        step = 1.0f / fmaxf(1.15f * L, 1e-12f);
    }
    float sb8[8];
    #pragma unroll
    for (int t = 0; t < 8; ++t) sb8[t] = step * b8[t];

    // ---- FISTA: rows {16t+fm} per lane; per-quad update+publish under next quad's MFMAs ----
    if (l < 16) {
        #pragma unroll
        for (int t = 0; t < 8; ++t) yh[16 * t + l] = (_Float16)0.0f;   // y0 = 0
    }
    float lam8[8], yv8[8];
    #pragma unroll
    for (int t = 0; t < 8; ++t) { lam8[t] = 0.0f; yv8[t] = 0.0f; }
    float tk = 1.0f;
    for (int it = 0; it < NRUN; ++it) {
        load_ya();
        const float tkn = 0.5f * (1.0f + sqrtf(1.0f + 4.0f * tk * tk));
        const float bet = (tk - 1.0f) / tkn;
        #pragma unroll
        for (int tq = 0; tq < 2; ++tq) {
            f4 c[4];
            #pragma unroll
            for (int j = 0; j < 4; ++j) c[j] = (f4)0.0f;
            #pragma unroll
            for (int kt = 0; kt < 4; ++kt)
                #pragma unroll
                for (int j = 0; j < 4; ++j)
                    c[j] = __builtin_amdgcn_mfma_f32_16x16x32_f16(ya[kt], gb[4 * tq + j][kt], c[j], 0, 0, 0);
            #pragma unroll
            for (int j = 0; j < 4; ++j) {
                const int t = 4 * tq + j;
                const float ln = fmaxf(yv8[t] - step * c[j][0] + sb8[t], 0.0f);
                yv8[t] = ln + bet * (ln - lam8[t]);
                lam8[t] = ln;
            }
            if (l < 16) {
                #pragma unroll
                for (int j = 0; j < 4; ++j) yh[16 * (4 * tq + j) + l] = (_Float16)yv8[4 * tq + j];
            }
        }
        tk = tkn;
    }

    // ---- cosine via lam^T b, lam^T G lam, ||p|| ----
    if (l < 16) {
        #pragma unroll
        for (int t = 0; t < 8; ++t) yh[16 * t + l] = (_Float16)lam8[t];
    }
    {
        load_ya();                         // u = G lam (raw)
        f4 c[8];
        #pragma unroll
        for (int t = 0; t < 8; ++t) c[t] = (f4)0.0f;
        #pragma unroll
        for (int kt = 0; kt < 4; ++kt)
            #pragma unroll
            for (int t = 0; t < 8; ++t)
                c[t] = __builtin_amdgcn_mfma_f32_16x16x32_f16(ya[kt], gb[t][kt], c[t], 0, 0, 0);
        float xg = 0.0f, xb = 0.0f;
        if (l < 16) {
            #pragma unroll
            for (int t = 0; t < 8; ++t) { xg += lam8[t] * c[t][0]; xb += lam8[t] * b8[t]; }
        }
        const float sg_ = wsum(xg);
        const float sb_ = wsum(xb);
        if (tid == 0) {
            const float glg = sg_;                  // lam^T G lam
            const float np_ = sqrtf(fmaxf(glg, 0.0f));
            const float pdot = sb_ / (np_ + 1e-12f);
            const float qn = fmaxf(np_ / (np_ + 1e-12f), 1e-8f);
            const float pn = fmaxf(sqrtf(pn2), 1e-8f);
            const float c_ = pdot / (pn * qn);
            atomicAdd(out, -c_ * (1.0f / (float)BATCH));
        }
    }
}

extern "C" void kernel_launch(void* const* d_in, const int* in_sizes, int n_in,
                              void* d_out, int out_size, void* d_ws, size_t ws_size,
                              hipStream_t stream) {
    const float* pred = (const float*)d_in[0];  // (512, 512)
    const float* ctr  = (const float*)d_in[1];  // (512, 128, 512)
    float* out = (float*)d_out;

    (void)d_ws; (void)ws_size;                  // G never leaves the CU
    hipMemsetAsync(d_out, 0, out_size, stream); // capture-safe memset node (out accumulated via atomicAdd)
    fused_kernel<<<BATCH, 256, 0, stream>>>(pred, ctr, out);
}

// Round 11
// 229.574 us; speedup vs baseline: 1.0059x; 1.0059x over previous
//
#include <hip/hip_runtime.h>
#include <math.h>

// Problem constants
#define BATCH 512
#define M 128
#define D 512
#define PITER 9           // power iterations (L inflated 1.15x; converged lam is step-independent)
#define NRUN 58           // FISTA iterations (rate ~0.69 -> 0.69^58 ~ 4e-10; reference runs 400)
#define KC 64             // k-columns per staging chunk
#define NCH (D / KC)      // 8 chunks
#define SSTR 72           // staging row stride in halfs (144 B): 16B-aligned, even bank-quad spread
#define GSH 136           // G fp16 LDS row stride in halfs (272 B): 16B-aligned rows, 2-way banks
#define SCL 0.0009765625f // 2^-10 per-iteration power scaling

typedef __attribute__((ext_vector_type(8))) _Float16 h8;
typedef __attribute__((ext_vector_type(4))) float f4;

// ===== fused; build = 4-wave MFMA, solve = ONE wave, barrier-free =====
// r11 change: the solver wave is chosen PER BLOCK (wave 0 or wave 2) so the two
// co-resident blocks' solve waves land on DIFFERENT SIMDs (wave i -> SIMD i%4).
// With both solvers on SIMD 0 (r6/r10), the 32 MFMAs/iter (16 cyc/MFMA of SIMD
// matrix-pipe) of BOTH samples serialized on one SIMD ~= the measured 2000 cyc/iter.
__launch_bounds__(256, 2)
__global__ void fused_kernel(const float* __restrict__ pred,
                             const float* __restrict__ ctr,
                             float* __restrict__ out)
{
    // union{ fp16 staging 2x18432 B , fp16 G 128xGSH = 34816 B }
    __shared__ __align__(16) char uni[2 * M * SSTR * 2];   // 36864 B
    __shared__ __align__(16) float p_s[D];
    __shared__ __align__(16) _Float16 yh[M];               // y broadcast vector (fp16)
    __shared__ float mask_s[M];
    __shared__ float b_s[M];
    __shared__ float wredA[4];

    _Float16* hiS = (_Float16*)uni;                        // [2][M*SSTR] during build
    _Float16* g16 = (_Float16*)uni;                        // [M][GSH] after build

    const int tid = threadIdx.x;
    const int blk = blockIdx.x;
    const int w = tid >> 6, l = tid & 63;                  // wave, lane
    const int row = tid >> 1;                              // staging row (0..127)
    const int sg = tid & 1;                                // 32-col half of the 64-col chunk
    const int fm = l & 15;                                 // MFMA fragment row/col
    const int fq = l >> 4;                                 // MFMA k-quad

    const float* predRow = pred + (size_t)blk * D;
    const float* ctrBase = ctr + (size_t)blk * (size_t)(M * D);

    // ---- stage p (2 elems/thread), ||p||^2 -> all threads (solver wave varies) ----
    float pv0 = predRow[tid];
    float pv1 = predRow[tid + 256];
    p_s[tid] = pv0;
    p_s[tid + 256] = pv1;
    float v = pv0 * pv0 + pv1 * pv1;
    #pragma unroll
    for (int off = 32; off > 0; off >>= 1) v += __shfl_xor(v, off, 64);
    if (l == 0) wredA[w] = v;
    __syncthreads();
    const float pn2 = wredA[0] + wredA[1] + wredA[2] + wredA[3];

    // ---- build: G = (masked C_fp16)(masked C_fp16)^T via MFMA, depth-2 prefetch ----
    f4 acc[2][8];
    #pragma unroll
    for (int i = 0; i < 2; ++i)
        #pragma unroll
        for (int jx = 0; jx < 8; ++jx)
            acc[i][jx] = (f4)0.0f;

    float rs = 0.0f, bp = 0.0f;
    const float* src = ctrBase + (size_t)row * D + 32 * sg;  // this thread's 32-col strip base
    f4 buf[3][8];                                            // 3-deep rotation (static idx via full unroll)
    #pragma unroll
    for (int j = 0; j < 8; ++j) buf[0][j] = *(const f4*)(src + 4 * j);
    #pragma unroll
    for (int j = 0; j < 8; ++j) buf[1][j] = *(const f4*)(src + 64 + 4 * j);

    #pragma unroll
    for (int kc = 0; kc < NCH; ++kc) {
        const int cb = kc % 3;
        _Float16* hc = hiS + (kc & 1) * (M * SSTR);
        // convert + stage 32 halfs
        #pragma unroll
        for (int j = 0; j < 4; ++j) {
            f4 x = buf[cb][2 * j], y = buf[cb][2 * j + 1];
            h8 hv = {(_Float16)x.x, (_Float16)x.y, (_Float16)x.z, (_Float16)x.w,
                     (_Float16)y.x, (_Float16)y.y, (_Float16)y.z, (_Float16)y.w};
            *(h8*)(hc + row * SSTR + 32 * sg + 8 * j) = hv;
        }
        // row-abs-sum and b-dot
        #pragma unroll
        for (int j = 0; j < 8; ++j) {
            f4 x = buf[cb][j];
            rs += fabsf(x.x) + fabsf(x.y) + fabsf(x.z) + fabsf(x.w);
            f4 pp = *(const f4*)(p_s + 64 * kc + 32 * sg + 4 * j);
            bp += x.x * pp.x + x.y * pp.y + x.z * pp.z + x.w * pp.w;
        }
        // issue chunk kc+2 loads BEFORE the barrier
        if (kc + 2 < NCH) {
            const int nb = (kc + 2) % 3;
            #pragma unroll
            for (int j = 0; j < 8; ++j) buf[nb][j] = *(const f4*)(src + 64 * (kc + 2) + 4 * j);
        }
        __syncthreads();   // staged data visible; dbuf -> 1 barrier/chunk
        // MFMA: rows [32w,32w+32) x all 128 cols
        #pragma unroll
        for (int ks = 0; ks < 2; ++ks) {
            h8 Ah[2];
            #pragma unroll
            for (int t = 0; t < 2; ++t)
                Ah[t] = *(const h8*)(hc + (32 * w + 16 * t + fm) * SSTR + 32 * ks + 8 * fq);
            #pragma unroll
            for (int tc = 0; tc < 8; ++tc) {
                h8 Bh = *(const h8*)(hc + (16 * tc + fm) * SSTR + 32 * ks + 8 * fq);
                acc[0][tc] = __builtin_amdgcn_mfma_f32_16x16x32_f16(Ah[0], Bh, acc[0][tc], 0, 0, 0);
                acc[1][tc] = __builtin_amdgcn_mfma_f32_16x16x32_f16(Ah[1], Bh, acc[1][tc], 0, 0, 0);
            }
        }
    }

    // ---- row mask + b (pairwise xor over the 2 col-halves) ----
    rs += __shfl_xor(rs, 1, 64);
    bp += __shfl_xor(bp, 1, 64);
    const bool okr = rs > 1e-7f;
    if (sg == 0) {
        mask_s[row] = okr ? 1.0f : 0.0f;
        b_s[row] = okr ? -bp : 0.0f;      // b = C_masked * (-pred)
    }
    if (tid < M) yh[tid] = (_Float16)1.0f;   // power-iteration v0 = ones
    __syncthreads();   // mask/b/y0 ready; hiS dead -> g16 may overwrite

    // hoist masks (C/D layout: col=lane&15, row=(lane>>4)*4+reg)
    float mc[8], mr[2][4];
    #pragma unroll
    for (int tc = 0; tc < 8; ++tc) mc[tc] = mask_s[16 * tc + fm];
    #pragma unroll
    for (int t = 0; t < 2; ++t)
        #pragma unroll
        for (int r = 0; r < 4; ++r) mr[t][r] = mask_s[32 * w + 16 * t + 4 * fq + r];

    // ---- masked G -> fp16 LDS, full 128x128, single barrier ----
    #pragma unroll
    for (int t = 0; t < 2; ++t)
        #pragma unroll
        for (int r = 0; r < 4; ++r) {
            const int grow = 32 * w + 16 * t + 4 * fq + r;
            const float mrr = mr[t][r];
            #pragma unroll
            for (int tc = 0; tc < 8; ++tc)
                g16[grow * GSH + 16 * tc + fm] = (_Float16)(acc[t][tc][r] * mrr * mc[tc]);
        }
    __syncthreads();

    // solver wave: 0 or 2 by block index, so co-resident blocks' solvers land on
    // different SIMDs (covers (b,b+256) and (b,b+1) co-residency pairings)
    const int sv = (((blk >> 8) ^ blk) & 1) << 1;
    if (w != sv) return;    // other waves done; no barriers below (wave-internal only)

    // ---- solo solve on wave sv ----
    // B-frags of G (symmetric): gb[t][kt] = G[16t+fm][32kt+8fq .. +8)  (128 regs)
    h8 gb[8][4];
    #pragma unroll
    for (int t = 0; t < 8; ++t)
        #pragma unroll
        for (int kt = 0; kt < 4; ++kt)
            gb[t][kt] = *(const h8*)(g16 + (16 * t + fm) * GSH + 32 * kt + 8 * fq);

    float b8[8];
    #pragma unroll
    for (int t = 0; t < 8; ++t) b8[t] = b_s[16 * t + fm];

    h8 ya[4];
    // fence + load ya: one LDS drain per iteration; sched_barrier per rule #18
    auto load_ya = [&]() {
        asm volatile("s_waitcnt lgkmcnt(0)" ::: "memory");
        __builtin_amdgcn_sched_barrier(0);
        #pragma unroll
        for (int kt = 0; kt < 4; ++kt) ya[kt] = *(const h8*)(yh + 32 * kt + 8 * fq);
    };
    auto wsum = [&](float x) {
        #pragma unroll
        for (int off = 1; off < 64; off <<= 1) x += __shfl_xor(x, off, 64);
        return x;
    };

    // ---- power iteration (unnormalized, 2^-10 per-step scaling) ----
    float v8[8];
    #pragma unroll
    for (int t = 0; t < 8; ++t) v8[t] = 1.0f;
    for (int it = 0; it < PITER; ++it) {
        load_ya();
        #pragma unroll
        for (int tq = 0; tq < 2; ++tq) {
            f4 c[4];
            #pragma unroll
            for (int j = 0; j < 4; ++j) c[j] = (f4)0.0f;
            #pragma unroll
            for (int kt = 0; kt < 4; ++kt)
                #pragma unroll
                for (int j = 0; j < 4; ++j)
                    c[j] = __builtin_amdgcn_mfma_f32_16x16x32_f16(ya[kt], gb[4 * tq + j][kt], c[j], 0, 0, 0);
            #pragma unroll
            for (int j = 0; j < 4; ++j) v8[4 * tq + j] = c[j][0] * SCL;
            if (l < 16) {
                #pragma unroll
                for (int j = 0; j < 4; ++j) yh[16 * (4 * tq + j) + l] = (_Float16)v8[4 * tq + j];
            }
        }
    }
    float u8[8];
    float step;
    {
        load_ya();                         // u = G v (raw)
        f4 c[8];
        #pragma unroll
        for (int t = 0; t < 8; ++t) c[t] = (f4)0.0f;
        #pragma unroll
        for (int kt = 0; kt < 4; ++kt)
            #pragma unroll
            for (int t = 0; t < 8; ++t)
                c[t] = __builtin_amdgcn_mfma_f32_16x16x32_f16(ya[kt], gb[t][kt], c[t], 0, 0, 0);
        #pragma unroll
        for (int t = 0; t < 8; ++t) u8[t] = c[t][0];
        float xv = 0.0f, xu = 0.0f;
        if (l < 16) {                      // rows counted once (fq==0 lanes)
            #pragma unroll
            for (int t = 0; t < 8; ++t) { xv += v8[t] * v8[t]; xu += u8[t] * u8[t]; }
        }
        const float nv = wsum(xv);
        const float nu = wsum(xu);
        const float L = sqrtf(nu / fmaxf(nv, 1e-30f));
        step = 1.0f / fmaxf(1.15f * L, 1e-12f);
    }
    float sb8[8];
    #pragma unroll
    for (int t = 0; t < 8; ++t) sb8[t] = step * b8[t];

    // ---- FISTA: rows {16t+fm} per lane; per-quad update+publish under next quad's MFMAs ----
    if (l < 16) {
        #pragma unroll
        for (int t = 0; t < 8; ++t) yh[16 * t + l] = (_Float16)0.0f;   // y0 = 0
    }
    float lam8[8], yv8[8];
    #pragma unroll
    for (int t = 0; t < 8; ++t) { lam8[t] = 0.0f; yv8[t] = 0.0f; }
    float tk = 1.0f;
    for (int it = 0; it < NRUN; ++it) {
        load_ya();
        const float tkn = 0.5f * (1.0f + sqrtf(1.0f + 4.0f * tk * tk));
        const float bet = (tk - 1.0f) / tkn;
        #pragma unroll
        for (int tq = 0; tq < 2; ++tq) {
            f4 c[4];
            #pragma unroll
            for (int j = 0; j < 4; ++j) c[j] = (f4)0.0f;
            #pragma unroll
            for (int kt = 0; kt < 4; ++kt)
                #pragma unroll
                for (int j = 0; j < 4; ++j)
                    c[j] = __builtin_amdgcn_mfma_f32_16x16x32_f16(ya[kt], gb[4 * tq + j][kt], c[j], 0, 0, 0);
            #pragma unroll
            for (int j = 0; j < 4; ++j) {
                const int t = 4 * tq + j;
                const float ln = fmaxf(yv8[t] - step * c[j][0] + sb8[t], 0.0f);
                yv8[t] = ln + bet * (ln - lam8[t]);
                lam8[t] = ln;
            }
            if (l < 16) {
                #pragma unroll
                for (int j = 0; j < 4; ++j) yh[16 * (4 * tq + j) + l] = (_Float16)yv8[4 * tq + j];
            }
        }
        tk = tkn;
    }

    // ---- cosine via lam^T b, lam^T G lam, ||p|| ----
    if (l < 16) {
        #pragma unroll
        for (int t = 0; t < 8; ++t) yh[16 * t + l] = (_Float16)lam8[t];
    }
    {
        load_ya();                         // u = G lam (raw)
        f4 c[8];
        #pragma unroll
        for (int t = 0; t < 8; ++t) c[t] = (f4)0.0f;
        #pragma unroll
        for (int kt = 0; kt < 4; ++kt)
            #pragma unroll
            for (int t = 0; t < 8; ++t)
                c[t] = __builtin_amdgcn_mfma_f32_16x16x32_f16(ya[kt], gb[t][kt], c[t], 0, 0, 0);
        float xg = 0.0f, xb = 0.0f;
        if (l < 16) {
            #pragma unroll
            for (int t = 0; t < 8; ++t) { xg += lam8[t] * c[t][0]; xb += lam8[t] * b8[t]; }
        }
        const float sg_ = wsum(xg);
        const float sb_ = wsum(xb);
        if (l == 0) {
            const float glg = sg_;                  // lam^T G lam
            const float np_ = sqrtf(fmaxf(glg, 0.0f));
            const float pdot = sb_ / (np_ + 1e-12f);
            const float qn = fmaxf(np_ / (np_ + 1e-12f), 1e-8f);
            const float pn = fmaxf(sqrtf(pn2), 1e-8f);
            const float c_ = pdot / (pn * qn);
            atomicAdd(out, -c_ * (1.0f / (float)BATCH));
        }
    }
}

extern "C" void kernel_launch(void* const* d_in, const int* in_sizes, int n_in,
                              void* d_out, int out_size, void* d_ws, size_t ws_size,
                              hipStream_t stream) {
    const float* pred = (const float*)d_in[0];  // (512, 512)
    const float* ctr  = (const float*)d_in[1];  // (512, 128, 512)
    float* out = (float*)d_out;

    (void)d_ws; (void)ws_size;                  // G never leaves the CU
    hipMemsetAsync(d_out, 0, out_size, stream); // capture-safe memset node (out accumulated via atomicAdd)
    fused_kernel<<<BATCH, 256, 0, stream>>>(pred, ctr, out);
}

// Round 12
// 228.927 us; speedup vs baseline: 1.0087x; 1.0028x over previous
//
#include <hip/hip_runtime.h>
#include <math.h>

// Problem constants
#define BATCH 512
#define M 128
#define D 512
#define PITER 9           // power iterations (L inflated 1.15x; converged lam is step-independent)
#define NRUN 58           // FISTA iterations (rate ~0.69 -> 0.69^58 ~ 4e-10; reference runs 400)
#define KC 64             // k-columns per staging chunk
#define NCH (D / KC)      // 8 chunks
#define SSTR 72           // staging row stride in halfs (144 B): 16B-aligned, even bank-quad spread
#define GSH 136           // G fp16 LDS row stride in halfs (272 B): 16B-aligned rows, 2-way banks
#define SCL 0.0009765625f // 2^-10 per-iteration power scaling

typedef __attribute__((ext_vector_type(8))) _Float16 h8;
typedef __attribute__((ext_vector_type(4))) float f4;

// ===== fused; build = 4-wave MFMA, solve = ONE wave, barrier-free =====
// r12 change: PIN the G register cache. r6-r11 all reported VGPR_Count=112 while
// gb[8][4] alone needs 128 VGPRs -> the compiler was REMATERIALIZING the 32
// ds_read_b128 of G inside every matvec (no scratch traffic, FETCH=input-size,
// so not spilled -- re-read from LDS). That is ~+1000 cyc/iter of LDS ops and
// explains why r10 (pipelining) and r11 (SIMD placement) were both neutral.
// A volatile "+v" no-op asm on each fragment forbids remat; live-set ~210 <= 256.
__launch_bounds__(256, 2)
__global__ void fused_kernel(const float* __restrict__ pred,
                             const float* __restrict__ ctr,
                             float* __restrict__ out)
{
    // union{ fp16 staging 2x18432 B , fp16 G 128xGSH = 34816 B }
    __shared__ __align__(16) char uni[2 * M * SSTR * 2];   // 36864 B
    __shared__ __align__(16) float p_s[D];
    __shared__ __align__(16) _Float16 yh[M];               // y broadcast vector (fp16)
    __shared__ float mask_s[M];
    __shared__ float b_s[M];
    __shared__ float wredA[4];

    _Float16* hiS = (_Float16*)uni;                        // [2][M*SSTR] during build
    _Float16* g16 = (_Float16*)uni;                        // [M][GSH] after build

    const int tid = threadIdx.x;
    const int blk = blockIdx.x;
    const int w = tid >> 6, l = tid & 63;                  // wave, lane
    const int row = tid >> 1;                              // staging row (0..127)
    const int sg = tid & 1;                                // 32-col half of the 64-col chunk
    const int fm = l & 15;                                 // MFMA fragment row/col
    const int fq = l >> 4;                                 // MFMA k-quad

    const float* predRow = pred + (size_t)blk * D;
    const float* ctrBase = ctr + (size_t)blk * (size_t)(M * D);

    // ---- stage p (2 elems/thread), ||p||^2 -> all threads (solver wave varies) ----
    float pv0 = predRow[tid];
    float pv1 = predRow[tid + 256];
    p_s[tid] = pv0;
    p_s[tid + 256] = pv1;
    float v = pv0 * pv0 + pv1 * pv1;
    #pragma unroll
    for (int off = 32; off > 0; off >>= 1) v += __shfl_xor(v, off, 64);
    if (l == 0) wredA[w] = v;
    __syncthreads();
    const float pn2 = wredA[0] + wredA[1] + wredA[2] + wredA[3];

    // ---- build: G = (masked C_fp16)(masked C_fp16)^T via MFMA, depth-2 prefetch ----
    f4 acc[2][8];
    #pragma unroll
    for (int i = 0; i < 2; ++i)
        #pragma unroll
        for (int jx = 0; jx < 8; ++jx)
            acc[i][jx] = (f4)0.0f;

    float rs = 0.0f, bp = 0.0f;
    const float* src = ctrBase + (size_t)row * D + 32 * sg;  // this thread's 32-col strip base
    f4 buf[3][8];                                            // 3-deep rotation (static idx via full unroll)
    #pragma unroll
    for (int j = 0; j < 8; ++j) buf[0][j] = *(const f4*)(src + 4 * j);
    #pragma unroll
    for (int j = 0; j < 8; ++j) buf[1][j] = *(const f4*)(src + 64 + 4 * j);

    #pragma unroll
    for (int kc = 0; kc < NCH; ++kc) {
        const int cb = kc % 3;
        _Float16* hc = hiS + (kc & 1) * (M * SSTR);
        // convert + stage 32 halfs
        #pragma unroll
        for (int j = 0; j < 4; ++j) {
            f4 x = buf[cb][2 * j], y = buf[cb][2 * j + 1];
            h8 hv = {(_Float16)x.x, (_Float16)x.y, (_Float16)x.z, (_Float16)x.w,
                     (_Float16)y.x, (_Float16)y.y, (_Float16)y.z, (_Float16)y.w};
            *(h8*)(hc + row * SSTR + 32 * sg + 8 * j) = hv;
        }
        // row-abs-sum and b-dot
        #pragma unroll
        for (int j = 0; j < 8; ++j) {
            f4 x = buf[cb][j];
            rs += fabsf(x.x) + fabsf(x.y) + fabsf(x.z) + fabsf(x.w);
            f4 pp = *(const f4*)(p_s + 64 * kc + 32 * sg + 4 * j);
            bp += x.x * pp.x + x.y * pp.y + x.z * pp.z + x.w * pp.w;
        }
        // issue chunk kc+2 loads BEFORE the barrier
        if (kc + 2 < NCH) {
            const int nb = (kc + 2) % 3;
            #pragma unroll
            for (int j = 0; j < 8; ++j) buf[nb][j] = *(const f4*)(src + 64 * (kc + 2) + 4 * j);
        }
        __syncthreads();   // staged data visible; dbuf -> 1 barrier/chunk
        // MFMA: rows [32w,32w+32) x all 128 cols
        #pragma unroll
        for (int ks = 0; ks < 2; ++ks) {
            h8 Ah[2];
            #pragma unroll
            for (int t = 0; t < 2; ++t)
                Ah[t] = *(const h8*)(hc + (32 * w + 16 * t + fm) * SSTR + 32 * ks + 8 * fq);
            #pragma unroll
            for (int tc = 0; tc < 8; ++tc) {
                h8 Bh = *(const h8*)(hc + (16 * tc + fm) * SSTR + 32 * ks + 8 * fq);
                acc[0][tc] = __builtin_amdgcn_mfma_f32_16x16x32_f16(Ah[0], Bh, acc[0][tc], 0, 0, 0);
                acc[1][tc] = __builtin_amdgcn_mfma_f32_16x16x32_f16(Ah[1], Bh, acc[1][tc], 0, 0, 0);
            }
        }
    }

    // ---- row mask + b (pairwise xor over the 2 col-halves) ----
    rs += __shfl_xor(rs, 1, 64);
    bp += __shfl_xor(bp, 1, 64);
    const bool okr = rs > 1e-7f;
    if (sg == 0) {
        mask_s[row] = okr ? 1.0f : 0.0f;
        b_s[row] = okr ? -bp : 0.0f;      // b = C_masked * (-pred)
    }
    if (tid < M) yh[tid] = (_Float16)1.0f;   // power-iteration v0 = ones
    __syncthreads();   // mask/b/y0 ready; hiS dead -> g16 may overwrite

    // hoist masks (C/D layout: col=lane&15, row=(lane>>4)*4+reg)
    float mc[8], mr[2][4];
    #pragma unroll
    for (int tc = 0; tc < 8; ++tc) mc[tc] = mask_s[16 * tc + fm];
    #pragma unroll
    for (int t = 0; t < 2; ++t)
        #pragma unroll
        for (int r = 0; r < 4; ++r) mr[t][r] = mask_s[32 * w + 16 * t + 4 * fq + r];

    // ---- masked G -> fp16 LDS, full 128x128, single barrier ----
    #pragma unroll
    for (int t = 0; t < 2; ++t)
        #pragma unroll
        for (int r = 0; r < 4; ++r) {
            const int grow = 32 * w + 16 * t + 4 * fq + r;
            const float mrr = mr[t][r];
            #pragma unroll
            for (int tc = 0; tc < 8; ++tc)
                g16[grow * GSH + 16 * tc + fm] = (_Float16)(acc[t][tc][r] * mrr * mc[tc]);
        }
    __syncthreads();

    // solver wave: 0 or 2 by block index (r11; neutral but harmless -- keep)
    const int sv = (((blk >> 8) ^ blk) & 1) << 1;
    if (w != sv) return;    // other waves done; no barriers below (wave-internal only)

    // ---- solo solve on wave sv ----
    // B-frags of G (symmetric): gb[t][kt] = G[16t+fm][32kt+8fq .. +8)  (128 VGPRs)
    // PINNED in registers: volatile "+v" asm makes each fragment the output of a
    // non-rerunnable op -> the compiler cannot rematerialize the ds_read per use.
    h8 gb[8][4];
    #pragma unroll
    for (int t = 0; t < 8; ++t)
        #pragma unroll
        for (int kt = 0; kt < 4; ++kt) {
            gb[t][kt] = *(const h8*)(g16 + (16 * t + fm) * GSH + 32 * kt + 8 * fq);
            f4 pin = __builtin_bit_cast(f4, gb[t][kt]);
            asm volatile("" : "+v"(pin));
            gb[t][kt] = __builtin_bit_cast(h8, pin);
        }

    float b8[8];
    #pragma unroll
    for (int t = 0; t < 8; ++t) b8[t] = b_s[16 * t + fm];

    h8 ya[4];
    // fence + load ya: one LDS drain per iteration; sched_barrier per rule #18
    auto load_ya = [&]() {
        asm volatile("s_waitcnt lgkmcnt(0)" ::: "memory");
        __builtin_amdgcn_sched_barrier(0);
        #pragma unroll
        for (int kt = 0; kt < 4; ++kt) ya[kt] = *(const h8*)(yh + 32 * kt + 8 * fq);
    };
    auto wsum = [&](float x) {
        #pragma unroll
        for (int off = 1; off < 64; off <<= 1) x += __shfl_xor(x, off, 64);
        return x;
    };

    // ---- power iteration (unnormalized, 2^-10 per-step scaling) ----
    float v8[8];
    #pragma unroll
    for (int t = 0; t < 8; ++t) v8[t] = 1.0f;
    for (int it = 0; it < PITER; ++it) {
        load_ya();
        #pragma unroll
        for (int tq = 0; tq < 2; ++tq) {
            f4 c[4];
            #pragma unroll
            for (int j = 0; j < 4; ++j) c[j] = (f4)0.0f;
            #pragma unroll
            for (int kt = 0; kt < 4; ++kt)
                #pragma unroll
                for (int j = 0; j < 4; ++j)
                    c[j] = __builtin_amdgcn_mfma_f32_16x16x32_f16(ya[kt], gb[4 * tq + j][kt], c[j], 0, 0, 0);
            #pragma unroll
            for (int j = 0; j < 4; ++j) v8[4 * tq + j] = c[j][0] * SCL;
            if (l < 16) {
                #pragma unroll
                for (int j = 0; j < 4; ++j) yh[16 * (4 * tq + j) + l] = (_Float16)v8[4 * tq + j];
            }
        }
    }
    float u8[8];
    float step;
    {
        load_ya();                         // u = G v (raw)
        f4 c[8];
        #pragma unroll
        for (int t = 0; t < 8; ++t) c[t] = (f4)0.0f;
        #pragma unroll
        for (int kt = 0; kt < 4; ++kt)
            #pragma unroll
            for (int t = 0; t < 8; ++t)
                c[t] = __builtin_amdgcn_mfma_f32_16x16x32_f16(ya[kt], gb[t][kt], c[t], 0, 0, 0);
        #pragma unroll
        for (int t = 0; t < 8; ++t) u8[t] = c[t][0];
        float xv = 0.0f, xu = 0.0f;
        if (l < 16) {                      // rows counted once (fq==0 lanes)
            #pragma unroll
            for (int t = 0; t < 8; ++t) { xv += v8[t] * v8[t]; xu += u8[t] * u8[t]; }
        }
        const float nv = wsum(xv);
        const float nu = wsum(xu);
        const float L = sqrtf(nu / fmaxf(nv, 1e-30f));
        step = 1.0f / fmaxf(1.15f * L, 1e-12f);
    }
    float sb8[8];
    #pragma unroll
    for (int t = 0; t < 8; ++t) sb8[t] = step * b8[t];

    // ---- FISTA: rows {16t+fm} per lane; per-quad update+publish under next quad's MFMAs ----
    if (l < 16) {
        #pragma unroll
        for (int t = 0; t < 8; ++t) yh[16 * t + l] = (_Float16)0.0f;   // y0 = 0
    }
    float lam8[8], yv8[8];
    #pragma unroll
    for (int t = 0; t < 8; ++t) { lam8[t] = 0.0f; yv8[t] = 0.0f; }
    float tk = 1.0f;
    for (int it = 0; it < NRUN; ++it) {
        load_ya();
        const float tkn = 0.5f * (1.0f + sqrtf(1.0f + 4.0f * tk * tk));
        const float bet = (tk - 1.0f) / tkn;
        #pragma unroll
        for (int tq = 0; tq < 2; ++tq) {
            f4 c[4];
            #pragma unroll
            for (int j = 0; j < 4; ++j) c[j] = (f4)0.0f;
            #pragma unroll
            for (int kt = 0; kt < 4; ++kt)
                #pragma unroll
                for (int j = 0; j < 4; ++j)
                    c[j] = __builtin_amdgcn_mfma_f32_16x16x32_f16(ya[kt], gb[4 * tq + j][kt], c[j], 0, 0, 0);
            #pragma unroll
            for (int j = 0; j < 4; ++j) {
                const int t = 4 * tq + j;
                const float ln = fmaxf(yv8[t] - step * c[j][0] + sb8[t], 0.0f);
                yv8[t] = ln + bet * (ln - lam8[t]);
                lam8[t] = ln;
            }
            if (l < 16) {
                #pragma unroll
                for (int j = 0; j < 4; ++j) yh[16 * (4 * tq + j) + l] = (_Float16)yv8[4 * tq + j];
            }
        }
        tk = tkn;
    }

    // ---- cosine via lam^T b, lam^T G lam, ||p|| ----
    if (l < 16) {
        #pragma unroll
        for (int t = 0; t < 8; ++t) yh[16 * t + l] = (_Float16)lam8[t];
    }
    {
        load_ya();                         // u = G lam (raw)
        f4 c[8];
        #pragma unroll
        for (int t = 0; t < 8; ++t) c[t] = (f4)0.0f;
        #pragma unroll
        for (int kt = 0; kt < 4; ++kt)
            #pragma unroll
            for (int t = 0; t < 8; ++t)
                c[t] = __builtin_amdgcn_mfma_f32_16x16x32_f16(ya[kt], gb[t][kt], c[t], 0, 0, 0);
        float xg = 0.0f, xb = 0.0f;
        if (l < 16) {
            #pragma unroll
            for (int t = 0; t < 8; ++t) { xg += lam8[t] * c[t][0]; xb += lam8[t] * b8[t]; }
        }
        const float sg_ = wsum(xg);
        const float sb_ = wsum(xb);
        if (l == 0) {
            const float glg = sg_;                  // lam^T G lam
            const float np_ = sqrtf(fmaxf(glg, 0.0f));
            const float pdot = sb_ / (np_ + 1e-12f);
            const float qn = fmaxf(np_ / (np_ + 1e-12f), 1e-8f);
            const float pn = fmaxf(sqrtf(pn2), 1e-8f);
            const float c_ = pdot / (pn * qn);
            atomicAdd(out, -c_ * (1.0f / (float)BATCH));
        }
    }
}

extern "C" void kernel_launch(void* const* d_in, const int* in_sizes, int n_in,
                              void* d_out, int out_size, void* d_ws, size_t ws_size,
                              hipStream_t stream) {
    const float* pred = (const float*)d_in[0];  // (512, 512)
    const float* ctr  = (const float*)d_in[1];  // (512, 128, 512)
    float* out = (float*)d_out;

    (void)d_ws; (void)ws_size;                  // G never leaves the CU
    hipMemsetAsync(d_out, 0, out_size, stream); // capture-safe memset node (out accumulated via atomicAdd)
    fused_kernel<<<BATCH, 256, 0, stream>>>(pred, ctr, out);
}